// Round 1
// baseline (1577.731 us; speedup 1.0000x reference)
//
#include <hip/hip_runtime.h>
#include <math.h>

#define NB 2048
#define ND 512
#define NG 8
#define NITER 64

#define LOG2E 1.4426950408889634f
#define LN2   0.6931471805599453f
#define NEGINF (-__builtin_inff())

__device__ __forceinline__ float fexp2(float x) { return __builtin_amdgcn_exp2f(x); }
__device__ __forceinline__ float flog2(float x) { return __builtin_amdgcn_logf(x); }

// ---- online logsumexp helpers (log2 domain) ----
__device__ __forceinline__ void online1(float& m, float& s, float t) {
  float M = fmaxf(m, t);
  s = fmaf(s, fexp2(m - M), fexp2(t - M));
  m = M;
}
__device__ __forceinline__ void online4(float& m, float& s, float t0, float t1, float t2, float t3) {
  float M4 = fmaxf(fmaxf(t0, t1), fmaxf(t2, t3));
  float M  = fmaxf(m, M4);
  float e = fexp2(t0 - M) + fexp2(t1 - M) + fexp2(t2 - M) + fexp2(t3 - M);
  s = fmaf(s, fexp2(m - M), e);
  m = M;
}
// max-butterfly -> one rescale -> sum-butterfly; all lanes end with (m,s)
__device__ __forceinline__ void wave_lse_reduce(float& m, float& s) {
  float M = m;
  #pragma unroll
  for (int o = 32; o; o >>= 1) M = fmaxf(M, __shfl_xor(M, o));
  float sv = (M == NEGINF) ? 0.f : s * fexp2(m - M);
  #pragma unroll
  for (int o = 32; o; o >>= 1) sv += __shfl_xor(sv, o);
  m = M; s = sv;
}
__device__ __forceinline__ void group8_lse_reduce(float& m, float& s) {
  float M = m;
  #pragma unroll
  for (int o = 4; o; o >>= 1) M = fmaxf(M, __shfl_xor(M, o, 8));
  float sv = (M == NEGINF) ? 0.f : s * fexp2(m - M);
  #pragma unroll
  for (int o = 4; o; o >>= 1) sv += __shfl_xor(sv, o, 8);
  m = M; s = sv;
}

// ---- setup: subgroup histogram, stable counting sort, zero-init ----
__global__ __launch_bounds__(256) void k_setup(
    const int* __restrict__ sub_raw,
    int* __restrict__ order, int* __restrict__ pgroup,
    int* __restrict__ counts, int* __restrict__ starts,
    float* __restrict__ lc2, unsigned int* __restrict__ cmax,
    float* __restrict__ gpot, float* __restrict__ f,
    float* __restrict__ fxx0, float* __restrict__ fyy0) {
  __shared__ int subs[NB];
  __shared__ int cnt[NG];
  __shared__ int st[NG + 1];
  __shared__ int odd_nz;
  const int t = threadIdx.x;
  if (t == 0) odd_nz = 0;
  if (t < NG) cnt[t] = 0;
  __syncthreads();
  // int64-vs-int32 heuristic: int64 values <8 have zero high words at odd int32 slots
  int nz = 0;
  for (int k = t; k < 1024; k += 256) nz |= (sub_raw[2 * k + 1] != 0) ? 1 : 0;
  if (nz) atomicOr(&odd_nz, 1);
  __syncthreads();
  const int stride = odd_nz ? 1 : 2;
  for (int i = t; i < NB; i += 256) {
    int g = sub_raw[(size_t)i * stride] & 7;
    subs[i] = g;
    atomicAdd(&cnt[g], 1);
  }
  __syncthreads();
  if (t == 0) {
    int a = 0;
    for (int g = 0; g < NG; ++g) { st[g] = a; a += cnt[g]; }
    st[NG] = a;
  }
  __syncthreads();
  // deterministic stable rank (lockstep LDS broadcast reads)
  for (int i = t; i < NB; i += 256) {
    int g = subs[i];
    int r = 0;
    for (int j = 0; j < i; ++j) r += (subs[j] == g) ? 1 : 0;
    int pos = st[g] + r;
    order[pos] = i;
    pgroup[pos] = g;
  }
  if (t < NG) {
    counts[t] = cnt[t];
    int c = cnt[t] < 1 ? 1 : cnt[t];
    lc2[t] = -flog2((float)c);   // -log2(cnt_g)
  }
  if (t < NG + 1) starts[t] = st[t];
  if (t == 0) *cmax = 0u;
  for (int i = t; i < NG * NB; i += 256) gpot[i] = 0.f;
  for (int i = t; i < NB; i += 256) { f[i] = 0.f; fxx0[i] = 0.f; fyy0[i] = 0.f; }
}

// ---- permute features by sorted order + row norms ----
__global__ __launch_bounds__(128) void k_permute(
    const float* __restrict__ X, const int* __restrict__ order,
    float* __restrict__ Xp, float* __restrict__ norms) {
  const int i = blockIdx.x, t = threadIdx.x;
  const int src = order[i];
  float4 v = ((const float4*)(X + (size_t)src * ND))[t];
  ((float4*)(Xp + (size_t)i * ND))[t] = v;
  float ss = v.x * v.x + v.y * v.y + v.z * v.z + v.w * v.w;
  #pragma unroll
  for (int o = 32; o; o >>= 1) ss += __shfl_xor(ss, o);
  __shared__ float p[2];
  if ((t & 63) == 0) p[t >> 6] = ss;
  __syncthreads();
  if (t == 0) norms[i] = p[0] + p[1];
}

// ---- C = 0.5*relu(n_i + n_j - 2 Xp Xp^T), plus global max (diam) ----
__global__ __launch_bounds__(256) void k_gemm(
    const float* __restrict__ Xp, const float* __restrict__ norms,
    float* __restrict__ C, unsigned int* __restrict__ cmax) {
  __shared__ __align__(16) float As[32][132];
  __shared__ __align__(16) float Bs[32][132];
  const int t = threadIdx.x;
  const int tx = t & 15, ty = t >> 4;
  const int i0 = blockIdx.y * 128, j0 = blockIdx.x * 128;
  float acc[8][8];
  #pragma unroll
  for (int r = 0; r < 8; ++r)
    #pragma unroll
    for (int c = 0; c < 8; ++c) acc[r][c] = 0.f;
  for (int k0 = 0; k0 < ND; k0 += 32) {
    #pragma unroll
    for (int l = 0; l < 4; ++l) {
      int flat = t + 256 * l;          // 0..1023
      int row = flat >> 3, c4 = flat & 7;
      float4 av = *(const float4*)(Xp + (size_t)(i0 + row) * ND + k0 + c4 * 4);
      As[c4 * 4 + 0][row] = av.x; As[c4 * 4 + 1][row] = av.y;
      As[c4 * 4 + 2][row] = av.z; As[c4 * 4 + 3][row] = av.w;
      float4 bv = *(const float4*)(Xp + (size_t)(j0 + row) * ND + k0 + c4 * 4);
      Bs[c4 * 4 + 0][row] = bv.x; Bs[c4 * 4 + 1][row] = bv.y;
      Bs[c4 * 4 + 2][row] = bv.z; Bs[c4 * 4 + 3][row] = bv.w;
    }
    __syncthreads();
    #pragma unroll
    for (int kk = 0; kk < 32; ++kk) {
      float4 a0 = *(const float4*)&As[kk][ty * 8];
      float4 a1 = *(const float4*)&As[kk][ty * 8 + 4];
      float4 b0 = *(const float4*)&Bs[kk][tx * 8];
      float4 b1 = *(const float4*)&Bs[kk][tx * 8 + 4];
      float aa[8] = {a0.x, a0.y, a0.z, a0.w, a1.x, a1.y, a1.z, a1.w};
      float bb[8] = {b0.x, b0.y, b0.z, b0.w, b1.x, b1.y, b1.z, b1.w};
      #pragma unroll
      for (int r = 0; r < 8; ++r)
        #pragma unroll
        for (int c = 0; c < 8; ++c) acc[r][c] = fmaf(aa[r], bb[c], acc[r][c]);
    }
    __syncthreads();
  }
  float nj[8];
  #pragma unroll
  for (int c = 0; c < 8; ++c) nj[c] = norms[j0 + tx * 8 + c];
  float lmax = 0.f;
  #pragma unroll
  for (int r = 0; r < 8; ++r) {
    const int i = i0 + ty * 8 + r;
    const float ni = norms[i];
    float4 o[2];
    float* op = (float*)o;
    #pragma unroll
    for (int c = 0; c < 8; ++c) {
      float v = 0.5f * fmaxf(ni + nj[c] - 2.f * acc[r][c], 0.f);
      op[c] = v;
      lmax = fmaxf(lmax, v);
    }
    float4* dst = (float4*)(C + (size_t)i * NB + j0 + tx * 8);
    dst[0] = o[0]; dst[1] = o[1];
  }
  #pragma unroll
  for (int o = 32; o; o >>= 1) lmax = fmaxf(lmax, __shfl_xor(lmax, o));
  __shared__ float wmax[4];
  if ((t & 63) == 0) wmax[t >> 6] = lmax;
  __syncthreads();
  if (t == 0) {
    float m = fmaxf(fmaxf(wmax[0], wmax[1]), fmaxf(wmax[2], wmax[3]));
    atomicMax(cmax, __float_as_uint(m));   // C >= 0 so uint compare is order-preserving
  }
}

// ---- eps-annealing schedule ----
__global__ void k_sched(const unsigned int* __restrict__ cmax, float* __restrict__ eps_sched) {
  const int t = threadIdx.x;
  if (t < NITER) {
    float cm = __uint_as_float(*cmax);
    float diam = sqrtf(2.f * fmaxf(cm, 1e-12f));
    float sig = diam * fexp2((float)t * -0.15200309344504997f);  // log2(0.9)
    sig = fmaxf(sig, 0.05f);
    eps_sched[t] = sig * sig;
  }
}

// ---- pass1: f_new (dense), fxx_new (own segment), fyy_new (dense); 1 wave / row ----
__global__ __launch_bounds__(256) void k_pass1(
    const float* __restrict__ C, const float* __restrict__ gpot,
    const float* __restrict__ fxx_in, const float* __restrict__ fyy_in,
    float* __restrict__ f_out, float* __restrict__ fxx_out, float* __restrict__ fyy_out,
    const int* __restrict__ pgroup, const int* __restrict__ starts,
    const float* __restrict__ lc2, const float* __restrict__ eps_sched, int iter) {
  const int wave = threadIdx.x >> 6, lane = threadIdx.x & 63;
  const int i = blockIdx.x * 4 + wave;
  const float eps = eps_sched[iter];
  const float inv2 = LOG2E / eps;
  const float ninv2 = -inv2;
  const int gi = pgroup[i];
  const float lb2 = -11.0f;  // -log2(2048)
  const float* Crow = C + (size_t)i * NB;
  const float4* C4 = (const float4*)Crow;
  const float4* g4 = (const float4*)(gpot + (size_t)gi * NB);
  const float4* y4 = (const float4*)fyy_in;
  float mA = NEGINF, sA = 0.f, mY = NEGINF, sY = 0.f;
  #pragma unroll 2
  for (int r = 0; r < 8; ++r) {
    const int idx = r * 64 + lane;
    float4 c = C4[idx];
    float4 gv = g4[idx];
    float4 yv = y4[idx];
    float c0 = c.x * ninv2, c1 = c.y * ninv2, c2 = c.z * ninv2, c3 = c.w * ninv2;
    online4(mA, sA, fmaf(gv.x, inv2, lb2) + c0, fmaf(gv.y, inv2, lb2) + c1,
                    fmaf(gv.z, inv2, lb2) + c2, fmaf(gv.w, inv2, lb2) + c3);
    online4(mY, sY, fmaf(yv.x, inv2, lb2) + c0, fmaf(yv.y, inv2, lb2) + c1,
                    fmaf(yv.z, inv2, lb2) + c2, fmaf(yv.w, inv2, lb2) + c3);
  }
  const float lcg = lc2[gi];
  const int s0 = starts[gi], s1 = starts[gi + 1];
  float mX = NEGINF, sX = 0.f;
  for (int j = s0 + lane; j < s1; j += 64)
    online1(mX, sX, fmaf(fxx_in[j], inv2, lcg) + Crow[j] * ninv2);
  wave_lse_reduce(mA, sA);
  wave_lse_reduce(mY, sY);
  wave_lse_reduce(mX, sX);
  if (lane == 0) {
    f_out[i]  = -eps * ((mA + flog2(sA)) * LN2);
    fyy_out[i] = 0.5f * (fyy_in[i] - eps * ((mY + flog2(sY)) * LN2));
    fxx_out[i] = 0.5f * (fxx_in[i] - eps * ((mX + flog2(sX)) * LN2));
  }
}

// ---- pass2: g_new[g,i] for all g; 8-lane group per subgroup, 1 wave / row ----
__global__ __launch_bounds__(256) void k_pass2(
    const float* __restrict__ C, const float* __restrict__ f,
    float* __restrict__ gpot, const int* __restrict__ starts,
    const float* __restrict__ lc2, const float* __restrict__ eps_sched, int iter) {
  const int wave = threadIdx.x >> 6, lane = threadIdx.x & 63;
  const int i = blockIdx.x * 4 + wave;
  const float eps = eps_sched[iter];
  const float inv2 = LOG2E / eps;
  const float ninv2 = -inv2;
  const float* Crow = C + (size_t)i * NB;
  const int gl = lane >> 3, li = lane & 7;
  const float lcg = lc2[gl];
  const int s0 = starts[gl], s1 = starts[gl + 1];
  float m = NEGINF, s = 0.f;
  for (int j = s0 + li; j < s1; j += 8)
    online1(m, s, fmaf(f[j], inv2, lcg) + Crow[j] * ninv2);
  group8_lse_reduce(m, s);
  if (li == 0) gpot[(size_t)gl * NB + i] = -eps * ((m + flog2(s)) * LN2);
}

// ---- finalize: 25 reductions -> S_g, total ----
__global__ __launch_bounds__(256) void k_final(
    const float* __restrict__ f, const float* __restrict__ gpot,
    const float* __restrict__ fxx, const float* __restrict__ fyy,
    const int* __restrict__ counts, const int* __restrict__ starts,
    float* __restrict__ out) {
  __shared__ float acc4[4];
  __shared__ float results[25];
  const int t = threadIdx.x, lane = t & 63, wid = t >> 6;
  for (int q = 0; q < 25; ++q) {
    float v = 0.f;
    if (q < 8) {
      for (int i = starts[q] + t; i < starts[q + 1]; i += 256) v += f[i];
    } else if (q < 16) {
      const int g = q - 8;
      for (int i = starts[g] + t; i < starts[g + 1]; i += 256) v += fxx[i];
    } else if (q < 24) {
      const float* gp = gpot + (size_t)(q - 16) * NB;
      for (int i = t; i < NB; i += 256) v += gp[i];
    } else {
      for (int i = t; i < NB; i += 256) v += fyy[i];
    }
    #pragma unroll
    for (int o = 32; o; o >>= 1) v += __shfl_xor(v, o);
    __syncthreads();
    if (lane == 0) acc4[wid] = v;
    __syncthreads();
    if (t == 0) results[q] = acc4[0] + acc4[1] + acc4[2] + acc4[3];
  }
  __syncthreads();
  if (t == 0) {
    const float syy = results[24] / (float)NB;
    float tot = 0.f; int nv = 0;
    float sg[8];
    for (int g = 0; g < NG; ++g) {
      float cnt = (float)(counts[g] < 1 ? 1 : counts[g]);
      float S = (results[g] - results[8 + g]) / cnt + results[16 + g] / (float)NB - syy;
      int valid = counts[g] >= 2 ? 1 : 0;
      float sv = valid ? S : 0.f;
      sg[g] = sv;
      if (valid) { tot += sv; nv++; }
    }
    tot /= (float)(nv < 1 ? 1 : nv);
    out[0] = tot;
    for (int g = 0; g < NG; ++g) out[1 + g] = sg[g];
  }
}

extern "C" void kernel_launch(void* const* d_in, const int* in_sizes, int n_in,
                              void* d_out, int out_size, void* d_ws, size_t ws_size,
                              hipStream_t stream) {
  (void)in_sizes; (void)n_in; (void)out_size; (void)ws_size;
  const float* X = (const float*)d_in[0];
  const int* sub = (const int*)d_in[1];

  char* w = (char*)d_ws;
  size_t off = 0;
  auto alloc = [&](size_t bytes) -> void* {
    void* p = w + off;
    off = (off + bytes + 255) & ~(size_t)255;
    return p;
  };
  float* C      = (float*)alloc((size_t)NB * NB * 4);
  float* Xp     = (float*)alloc((size_t)NB * ND * 4);
  float* norms  = (float*)alloc(NB * 4);
  int*   order  = (int*)alloc(NB * 4);
  int*   pgroup = (int*)alloc(NB * 4);
  float* f      = (float*)alloc(NB * 4);
  float* gpot   = (float*)alloc((size_t)NG * NB * 4);
  float* fxx0   = (float*)alloc(NB * 4);
  float* fxx1   = (float*)alloc(NB * 4);
  float* fyy0   = (float*)alloc(NB * 4);
  float* fyy1   = (float*)alloc(NB * 4);
  float* eps    = (float*)alloc(NITER * 4);
  int*   counts = (int*)alloc(NG * 4);
  int*   starts = (int*)alloc((NG + 1) * 4);
  float* lc2    = (float*)alloc(NG * 4);
  unsigned int* cmax = (unsigned int*)alloc(4);

  k_setup<<<1, 256, 0, stream>>>(sub, order, pgroup, counts, starts, lc2, cmax,
                                 gpot, f, fxx0, fyy0);
  k_permute<<<NB, 128, 0, stream>>>(X, order, Xp, norms);
  k_gemm<<<dim3(16, 16), 256, 0, stream>>>(Xp, norms, C, cmax);
  k_sched<<<1, 64, 0, stream>>>(cmax, eps);
  for (int it = 0; it < NITER; ++it) {
    float* fxi = (it & 1) ? fxx1 : fxx0;
    float* fxo = (it & 1) ? fxx0 : fxx1;
    float* fyi = (it & 1) ? fyy1 : fyy0;
    float* fyo = (it & 1) ? fyy0 : fyy1;
    k_pass1<<<NB / 4, 256, 0, stream>>>(C, gpot, fxi, fyi, f, fxo, fyo,
                                        pgroup, starts, lc2, eps, it);
    k_pass2<<<NB / 4, 256, 0, stream>>>(C, f, gpot, starts, lc2, eps, it);
  }
  // after it=63 (odd), outputs landed in fxx0 / fyy0
  k_final<<<1, 256, 0, stream>>>(f, gpot, fxx0, fyy0, counts, starts, (float*)d_out);
}